// Round 11
// baseline (283.458 us; speedup 1.0000x reference)
//
#include <hip/hip_runtime.h>
#include <hip/hip_fp16.h>
#include <cstdint>
#include <cstddef>

#define NEG_SLOPE 0.2f
#define EPS_F 1e-16f
#define NBLKB 64

static __device__ __forceinline__ float leaky(float x) { return x > 0.f ? x : NEG_SLOPE * x; }

// ---------------- generic single-block exclusive scan ----------------

__global__ __launch_bounds__(1024) void scan_k(const int* __restrict__ cnt, int* __restrict__ off, int N) {
    __shared__ int wsum[16];
    int tid = threadIdx.x;
    int lane = tid & 63, wid = tid >> 6;
    int running = 0;
    for (int base = 0; base < N; base += 1024) {
        int i = base + tid;
        int v = (i < N) ? cnt[i] : 0;
        int iv = v;
        #pragma unroll
        for (int d = 1; d < 64; d <<= 1) {
            int t = __shfl_up(iv, d);
            if (lane >= d) iv += t;
        }
        if (lane == 63) wsum[wid] = iv;
        __syncthreads();
        if (tid < 16) {
            int s = wsum[tid];
            #pragma unroll
            for (int d = 1; d < 16; d <<= 1) {
                int t = __shfl_up(s, d);
                if (tid >= d) s += t;
            }
            wsum[tid] = s;
        }
        __syncthreads();
        int add = wid ? wsum[wid - 1] : 0;
        if (i < N) off[i + 1] = running + add + iv;
        int ct = wsum[15];
        __syncthreads();
        running += ct;
    }
    if (tid == 0) off[0] = 0;
}

// ---------------- bucketed CSR build ----------------

__global__ __launch_bounds__(256) void partB_k(const int* __restrict__ src, const int* __restrict__ dst,
                                               const int* __restrict__ starts, int* __restrict__ packed,
                                               int E, int nbuk) {
    __shared__ int lcnt[256];
    __shared__ int lbase[256];
    const int blk = blockIdx.x;
    for (int i = threadIdx.x; i < nbuk; i += 256) { lcnt[i] = 0; lbase[i] = starts[i * NBLKB + blk]; }
    __syncthreads();
    const int chunk = (E + NBLKB - 1) / NBLKB;
    const int base = blk * chunk, end = min(base + chunk, E);
    for (int i = base + (int)threadIdx.x; i < end; i += 256) {
        int d = dst[i], s = src[i];
        int b = d >> 8;
        int slot = atomicAdd(&lcnt[b], 1);
        packed[lbase[b] + slot] = s | ((d & 255) << 16);
    }
}

__global__ __launch_bounds__(256) void partC_k(const int* __restrict__ packed, const int* __restrict__ starts,
                                               int* __restrict__ off, int* __restrict__ esrc,
                                               int N, int E, int nbuk) {
    __shared__ int lcnt[256];
    __shared__ int lpre[256];
    const int b = blockIdx.x;
    const int bstart = starts[b * NBLKB];
    const int bend = (b + 1 < nbuk) ? starts[(b + 1) * NBLKB] : E;
    const int tid = threadIdx.x;
    lcnt[tid] = 0;
    __syncthreads();
    for (int i = bstart + tid; i < bend; i += 256) atomicAdd(&lcnt[packed[i] >> 16], 1);
    __syncthreads();
    if (tid < 64) {
        int v0 = lcnt[tid * 4], v1 = lcnt[tid * 4 + 1], v2 = lcnt[tid * 4 + 2], v3 = lcnt[tid * 4 + 3];
        int s = v0 + v1 + v2 + v3;
        int inc = s;
        #pragma unroll
        for (int d = 1; d < 64; d <<= 1) {
            int t = __shfl_up(inc, d);
            if (tid >= d) inc += t;
        }
        int ex = inc - s;
        lpre[tid * 4] = ex;
        lpre[tid * 4 + 1] = ex + v0;
        lpre[tid * 4 + 2] = ex + v0 + v1;
        lpre[tid * 4 + 3] = ex + v0 + v1 + v2;
    }
    __syncthreads();
    const int n0 = b << 8;
    const int nn = min(256, N - n0);
    if (tid < nn) off[n0 + tid] = bstart + lpre[tid];
    if (b == 0 && tid == 0) off[N] = E;
    lcnt[tid] = 0;
    __syncthreads();
    for (int i = bstart + tid; i < bend; i += 256) {
        int p = packed[i];
        int ld = p >> 16;
        int slot = atomicAdd(&lcnt[ld], 1);
        esrc[bstart + lpre[ld] + slot] = p & 0xFFFF;
    }
}

// ---------------- GEMM body (templated input type) ----------------

template <int M, int H, typename XT>
__device__ __forceinline__ void gemm_body(float* xsT, float* wt,
                                          const XT* __restrict__ X, const float* __restrict__ W,
                                          const float* __restrict__ a_s, const float* __restrict__ a_d,
                                          __half* __restrict__ O, float* __restrict__ aS,
                                          float* __restrict__ aD, int N, int bid) {
    constexpr int K = 128, BK = 16, ROWS = 128;
    constexpr int CPT = 8;
    constexpr int CT = M / CPT;
    constexpr int RPT = ROWS / (256 / CT);
    constexpr int XP = ROWS + 4;
    constexpr int C = M / H;
    constexpr int REDW = C / CPT;

    const int tid = threadIdx.x;
    const int cc = tid % CT;
    const int rr = tid / CT;
    const int row0 = bid * ROWS;

    float acc[RPT][CPT];
    #pragma unroll
    for (int r = 0; r < RPT; ++r)
        #pragma unroll
        for (int j = 0; j < CPT; ++j) acc[r][j] = 0.f;

    for (int k0 = 0; k0 < K; k0 += BK) {
        #pragma unroll
        for (int t = tid; t < ROWS * (BK / 4); t += 256) {
            int r = t >> 2;
            int kk = t & 3;
            int row = row0 + r;
            float4 v = make_float4(0.f, 0.f, 0.f, 0.f);
            if (row < N) {
                if constexpr (sizeof(XT) == 2) {
                    uint2 raw = *reinterpret_cast<const uint2*>(&X[(size_t)row * K + k0 + kk * 4]);
                    float2 fa = __half22float2(*reinterpret_cast<__half2*>(&raw.x));
                    float2 fb = __half22float2(*reinterpret_cast<__half2*>(&raw.y));
                    v = make_float4(fa.x, fa.y, fb.x, fb.y);
                } else {
                    v = *reinterpret_cast<const float4*>(&X[(size_t)row * K + k0 + kk * 4]);
                }
            }
            xsT[(kk * 4 + 0) * XP + r] = v.x;
            xsT[(kk * 4 + 1) * XP + r] = v.y;
            xsT[(kk * 4 + 2) * XP + r] = v.z;
            xsT[(kk * 4 + 3) * XP + r] = v.w;
        }
        #pragma unroll
        for (int t = tid; t < BK * (M / 4); t += 256) {
            int c4 = t % (M / 4);
            int k = t / (M / 4);
            *reinterpret_cast<float4*>(&wt[k * M + c4 * 4]) =
                *reinterpret_cast<const float4*>(&W[(size_t)(k0 + k) * M + c4 * 4]);
        }
        __syncthreads();
        #pragma unroll
        for (int k = 0; k < BK; ++k) {
            float xr[RPT];
            #pragma unroll
            for (int r4 = 0; r4 < RPT; r4 += 4) {
                float4 xv = *reinterpret_cast<const float4*>(&xsT[k * XP + rr * RPT + r4]);
                xr[r4 + 0] = xv.x; xr[r4 + 1] = xv.y; xr[r4 + 2] = xv.z; xr[r4 + 3] = xv.w;
            }
            float wv[CPT];
            #pragma unroll
            for (int c4 = 0; c4 < CPT; c4 += 4) {
                float4 w4 = *reinterpret_cast<const float4*>(&wt[k * M + cc * CPT + c4]);
                wv[c4 + 0] = w4.x; wv[c4 + 1] = w4.y; wv[c4 + 2] = w4.z; wv[c4 + 3] = w4.w;
            }
            #pragma unroll
            for (int r = 0; r < RPT; ++r)
                #pragma unroll
                for (int j = 0; j < CPT; ++j)
                    acc[r][j] = fmaf(xr[r], wv[j], acc[r][j]);
        }
        __syncthreads();
    }

    float asr[CPT], adr[CPT];
    #pragma unroll
    for (int c4 = 0; c4 < CPT; c4 += 4) {
        float4 t1 = *reinterpret_cast<const float4*>(a_s + cc * CPT + c4);
        asr[c4 + 0] = t1.x; asr[c4 + 1] = t1.y; asr[c4 + 2] = t1.z; asr[c4 + 3] = t1.w;
        float4 t2 = *reinterpret_cast<const float4*>(a_d + cc * CPT + c4);
        adr[c4 + 0] = t2.x; adr[c4 + 1] = t2.y; adr[c4 + 2] = t2.z; adr[c4 + 3] = t2.w;
    }
    const int head = (cc * CPT) / C;

    #pragma unroll
    for (int r = 0; r < RPT; ++r) {
        int row = row0 + rr * RPT + r;
        float ps = 0.f, pd = 0.f;
        #pragma unroll
        for (int j = 0; j < CPT; ++j) {
            ps = fmaf(acc[r][j], asr[j], ps);
            pd = fmaf(acc[r][j], adr[j], pd);
        }
        #pragma unroll
        for (int d = 1; d < REDW; d <<= 1) {
            ps += __shfl_xor(ps, d);
            pd += __shfl_xor(pd, d);
        }
        if (row < N) {
            __half2 p0 = __float22half2_rn(make_float2(acc[r][0], acc[r][1]));
            __half2 p1 = __float22half2_rn(make_float2(acc[r][2], acc[r][3]));
            __half2 p2 = __float22half2_rn(make_float2(acc[r][4], acc[r][5]));
            __half2 p3 = __float22half2_rn(make_float2(acc[r][6], acc[r][7]));
            uint4 pk;
            pk.x = *reinterpret_cast<unsigned*>(&p0);
            pk.y = *reinterpret_cast<unsigned*>(&p1);
            pk.z = *reinterpret_cast<unsigned*>(&p2);
            pk.w = *reinterpret_cast<unsigned*>(&p3);
            *reinterpret_cast<uint4*>(&O[(size_t)row * M + cc * CPT]) = pk;
            if ((cc & (REDW - 1)) == 0) {
                aS[(size_t)row * H + head] = ps;
                aD[(size_t)row * H + head] = pd;
            }
        }
    }
}

template <int M, int H, typename XT>
__global__ __launch_bounds__(256, 2) void gemm_k(const XT* __restrict__ X, const float* __restrict__ W,
                                                 const float* __restrict__ a_s, const float* __restrict__ a_d,
                                                 __half* __restrict__ O, float* __restrict__ aS,
                                                 float* __restrict__ aD, int N) {
    __shared__ float smem[16 * 132 + 16 * M];
    gemm_body<M, H, XT>(smem, smem + 16 * 132, X, W, a_s, a_d, O, aS, aD, N, blockIdx.x);
}

template <int M, int H>
__global__ __launch_bounds__(256, 2) void gemm_hist_k(const float* __restrict__ X, const float* __restrict__ W,
                                                      const float* __restrict__ a_s, const float* __restrict__ a_d,
                                                      __half* __restrict__ O, float* __restrict__ aS,
                                                      float* __restrict__ aD, int N,
                                                      const int* __restrict__ dst, int E,
                                                      int* __restrict__ cnts, int gemmGrid, int nbuk) {
    __shared__ float smem[16 * 132 + 16 * M];
    if ((int)blockIdx.x < gemmGrid) {
        gemm_body<M, H, float>(smem, smem + 16 * 132, X, W, a_s, a_d, O, aS, aD, N, blockIdx.x);
    } else {
        int* lcnt = (int*)smem;
        const int blk = blockIdx.x - gemmGrid;
        for (int i = threadIdx.x; i < nbuk; i += 256) lcnt[i] = 0;
        __syncthreads();
        const int chunk = (E + NBLKB - 1) / NBLKB;
        const int base = blk * chunk, end = min(base + chunk, E);
        for (int i = base + (int)threadIdx.x; i < end; i += 256) atomicAdd(&lcnt[dst[i] >> 8], 1);
        __syncthreads();
        for (int b = threadIdx.x; b < nbuk; b += 256) cnts[b * NBLKB + blk] = lcnt[b];
    }
}

// ---------------- channel-split segment aggregation ----------------
// NPASS channel slices; pass pinned to XCD via blockIdx%8 so each XCD's gathers
// stay inside a 3.2 MB L2-resident slice of h. 256-thread blocks, 2 nodes/wave,
// 32 lanes/node, 1 channel/lane (2B loads, exactly one 64B line per edge).

template <int H, int C, int NPASS, typename OutT>
__global__ __launch_bounds__(256) void agg_k(const __half* __restrict__ h, const float* __restrict__ aS,
                                             const float* __restrict__ aD, const int* __restrict__ off,
                                             const int* __restrict__ esrc, const float* __restrict__ bias,
                                             OutT* __restrict__ out, int N, int nodeBlocks) {
    constexpr int M = H * C;
    constexpr int PCH = M / NPASS;  // 32
    constexpr int SUBS = 8 / NPASS;
    static_assert(PCH == 32, "one channel per lane");
    __shared__ float wlds[4][2][32];

    const int G = blockIdx.x & 7;
    const int pass = G % NPASS;
    const int sub = G / NPASS;
    const int nb = ((int)blockIdx.x >> 3) * SUBS + sub;
    if (nb >= nodeBlocks) return;

    const int wslot = threadIdx.x >> 6;
    const int lane = threadIdx.x & 63;
    const int g = lane >> 5, lg = lane & 31;
    const int node = (nb * 4 + wslot) * 2 + g;
    const bool valid = node < N;
    const int nd = valid ? node : N - 1;

    const int ch = pass * PCH + lg;  // global channel
    const int hd = ch / C;           // head handled by this pass
    const float advh = aD[(size_t)nd * H + hd];
    const float asvh = aS[(size_t)nd * H + hd];
    const float es = leaky(asvh + advh);

    const int s0 = off[nd], s1 = off[nd + 1];
    const int deg = s1 - s0;

    if (__all(deg < 32)) {
        const int sv = (lg < deg) ? esrc[s0 + lg] : nd;
        const int cnt = deg + 1;
        const int cmax = max(cnt, __shfl_xor(cnt, 32));

        __half A[8], B[8], Cb[8];
        #pragma unroll
        for (int t = 0; t < 8; ++t) {
            int s = __shfl(sv, t, 32);
            A[t] = h[(size_t)s * M + ch];
        }
        if (cmax > 8) {
            #pragma unroll
            for (int t = 0; t < 8; ++t) {
                int s = __shfl(sv, 8 + t, 32);
                B[t] = h[(size_t)s * M + ch];
            }
        }
        if (cmax > 16) {
            #pragma unroll
            for (int t = 0; t < 8; ++t) {
                int s = __shfl(sv, 16 + t, 32);
                Cb[t] = h[(size_t)s * M + ch];
            }
        }
        // weight phase for this pass's head (overlaps the h loads)
        {
            float u = aS[(size_t)sv * H + hd];
            float w = (lg < deg) ? __expf(leaky(u + advh))
                    : (lg == deg) ? __expf(es) : 0.f;
            wlds[wslot][g][lg] = w;
        }
        asm volatile("s_waitcnt lgkmcnt(0)" ::: "memory");

        float acc = 0.f, wsum = 0.f;
        auto consume = [&](__half (&buf)[8], int j) {
            #pragma unroll
            for (int t = 0; t < 8; ++t) {
                float wq = wlds[wslot][g][j + t];
                wsum += wq;
                acc = fmaf(wq, __half2float(buf[t]), acc);
            }
        };
        consume(A, 0);
        if (cmax > 8) {
            if (cmax > 24) {
                #pragma unroll
                for (int t = 0; t < 8; ++t) {
                    int s = __shfl(sv, 24 + t, 32);
                    A[t] = h[(size_t)s * M + ch];
                }
            }
            consume(B, 8);
            if (cmax > 16) {
                consume(Cb, 16);
                if (cmax > 24) consume(A, 24);
            }
        }
        if (valid) {
            float o = acc / (wsum + EPS_F) + bias[ch];
            if constexpr (sizeof(OutT) == 2) {
                __half hv = __float2half_rn(o);
                __builtin_nontemporal_store(*reinterpret_cast<unsigned short*>(&hv),
                                            reinterpret_cast<unsigned short*>((__half*)out + (size_t)nd * M + ch));
            } else {
                __builtin_nontemporal_store(o, (float*)out + (size_t)nd * M + ch);
            }
        }
    } else {
        // fallback (deg >= 32): 32-lane group per node, online softmax on head hd
        if (valid) {
            float m = es, dsum = 0.f;
            for (int e = s0 + lg; e < s1; e += 32) {
                float uu = aS[(size_t)esrc[e] * H + hd];
                float ee = leaky(uu + advh);
                float nm = fmaxf(m, ee);
                dsum = dsum * __expf(m - nm) + __expf(ee - nm);
                m = nm;
            }
            #pragma unroll
            for (int d = 1; d < 32; d <<= 1) {
                float om = __shfl_xor(m, d, 32);
                float od = __shfl_xor(dsum, d, 32);
                float nm = fmaxf(m, om);
                dsum = dsum * __expf(m - nm) + od * __expf(om - nm);
                m = nm;
            }
            dsum += __expf(es - m);
            float acc = 0.f;
            for (int e = s0; e < s1; ++e) {
                int s = esrc[e];
                float wq = __expf(leaky(aS[(size_t)s * H + hd] + advh) - m);
                acc = fmaf(wq, __half2float(h[(size_t)s * M + ch]), acc);
            }
            acc = fmaf(__expf(es - m), __half2float(h[(size_t)nd * M + ch]), acc);
            float o = acc / (dsum + EPS_F) + bias[ch];
            if constexpr (sizeof(OutT) == 2) {
                ((__half*)out)[(size_t)nd * M + ch] = __float2half_rn(o);
            } else {
                ((float*)out)[(size_t)nd * M + ch] = o;
            }
        }
    }
}

// ---------------- launch ----------------

extern "C" void kernel_launch(void* const* d_in, const int* in_sizes, int n_in,
                              void* d_out, int out_size, void* d_ws, size_t ws_size,
                              hipStream_t stream) {
    const float* x   = (const float*)d_in[0];
    const int*   ei  = (const int*)d_in[1];
    const float* W0  = (const float*)d_in[2];
    const float* as0 = (const float*)d_in[3];
    const float* ad0 = (const float*)d_in[4];
    const float* b0  = (const float*)d_in[5];
    const float* W1  = (const float*)d_in[6];
    const float* as1 = (const float*)d_in[7];
    const float* ad1 = (const float*)d_in[8];
    const float* b1  = (const float*)d_in[9];
    const float* W2  = (const float*)d_in[10];
    const float* as2 = (const float*)d_in[11];
    const float* ad2 = (const float*)d_in[12];
    const float* b2  = (const float*)d_in[13];

    const int N = in_sizes[0] / 128;  // 50000
    const int E = in_sizes[1] / 2;    // 800000
    const int* esrc_in = ei;
    const int* edst_in = ei + E;
    const int NBUK = (N + 255) >> 8;  // 196

    char* w = (char*)d_ws;
    auto carve = [&](size_t bytes) -> char* {
        char* p = w;
        w += (bytes + 255) & ~(size_t)255;
        return p;
    };
    int*    off    = (int*)carve((size_t)(N + 1) * 4);
    int*    es     = (int*)carve((size_t)E * 4);
    int*    cnts   = (int*)carve((size_t)NBUK * NBLKB * 4);
    int*    starts = (int*)carve(((size_t)NBUK * NBLKB + 1) * 4);
    int*    packed = (int*)carve((size_t)E * 4);
    float*  aS     = (float*)carve((size_t)N * 4 * sizeof(float));
    float*  aD     = (float*)carve((size_t)N * 4 * sizeof(float));
    __half* bufH   = (__half*)carve((size_t)N * 128 * sizeof(__half));
    __half* bufO   = (__half*)carve((size_t)N * 128 * sizeof(__half));
    (void)ws_size; (void)n_in; (void)out_size;

    const int GEMM_GRID = (N + 127) / 128;
    const int NB = (N + 7) / 8;                 // node-blocks of 8 nodes
    const int GRID4 = ((NB + 1) / 2) * 8;       // NPASS=4 (SUBS=2)
    const int GRID2 = ((NB + 3) / 4) * 8;       // NPASS=2 (SUBS=4)

    gemm_hist_k<128, 4><<<GEMM_GRID + NBLKB, 256, 0, stream>>>(x, W0, as0, ad0, bufH, aS, aD, N,
                                                               edst_in, E, cnts, GEMM_GRID, NBUK);
    scan_k<<<1, 1024, 0, stream>>>(cnts, starts, NBUK * NBLKB);
    partB_k<<<NBLKB, 256, 0, stream>>>(esrc_in, edst_in, starts, packed, E, NBUK);
    partC_k<<<NBUK, 256, 0, stream>>>(packed, starts, off, es, N, E, NBUK);

    agg_k<4, 32, 4, __half><<<GRID4, 256, 0, stream>>>(bufH, aS, aD, off, es, b0, bufO, N, NB);

    gemm_k<128, 4, __half><<<GEMM_GRID, 256, 0, stream>>>(bufO, W1, as1, ad1, bufH, aS, aD, N);
    agg_k<4, 32, 4, __half><<<GRID4, 256, 0, stream>>>(bufH, aS, aD, off, es, b1, bufO, N, NB);

    gemm_k<64, 1, __half><<<GEMM_GRID, 256, 0, stream>>>(bufO, W2, as2, ad2, bufH, aS, aD, N);
    agg_k<1, 64, 2, float><<<GRID2, 256, 0, stream>>>(bufH, aS, aD, off, es, b2, (float*)d_out, N, NB);
}

// Round 12
// 249.334 us; speedup vs baseline: 1.1369x; 1.1369x over previous
//
#include <hip/hip_runtime.h>
#include <hip/hip_fp16.h>
#include <cstdint>
#include <cstddef>

#define NEG_SLOPE 0.2f
#define EPS_F 1e-16f
#define NBLKB 64

static __device__ __forceinline__ float leaky(float x) { return x > 0.f ? x : NEG_SLOPE * x; }

// ---------------- generic single-block exclusive scan ----------------

__global__ __launch_bounds__(1024) void scan_k(const int* __restrict__ cnt, int* __restrict__ off, int N) {
    __shared__ int wsum[16];
    int tid = threadIdx.x;
    int lane = tid & 63, wid = tid >> 6;
    int running = 0;
    for (int base = 0; base < N; base += 1024) {
        int i = base + tid;
        int v = (i < N) ? cnt[i] : 0;
        int iv = v;
        #pragma unroll
        for (int d = 1; d < 64; d <<= 1) {
            int t = __shfl_up(iv, d);
            if (lane >= d) iv += t;
        }
        if (lane == 63) wsum[wid] = iv;
        __syncthreads();
        if (tid < 16) {
            int s = wsum[tid];
            #pragma unroll
            for (int d = 1; d < 16; d <<= 1) {
                int t = __shfl_up(s, d);
                if (tid >= d) s += t;
            }
            wsum[tid] = s;
        }
        __syncthreads();
        int add = wid ? wsum[wid - 1] : 0;
        if (i < N) off[i + 1] = running + add + iv;
        int ct = wsum[15];
        __syncthreads();
        running += ct;
    }
    if (tid == 0) off[0] = 0;
}

// ---------------- bucketed CSR build ----------------

__global__ __launch_bounds__(256) void partB_k(const int* __restrict__ src, const int* __restrict__ dst,
                                               const int* __restrict__ starts, int* __restrict__ packed,
                                               int E, int nbuk) {
    __shared__ int lcnt[256];
    __shared__ int lbase[256];
    const int blk = blockIdx.x;
    for (int i = threadIdx.x; i < nbuk; i += 256) { lcnt[i] = 0; lbase[i] = starts[i * NBLKB + blk]; }
    __syncthreads();
    const int chunk = (E + NBLKB - 1) / NBLKB;
    const int base = blk * chunk, end = min(base + chunk, E);
    for (int i = base + (int)threadIdx.x; i < end; i += 256) {
        int d = dst[i], s = src[i];
        int b = d >> 8;
        int slot = atomicAdd(&lcnt[b], 1);
        packed[lbase[b] + slot] = s | ((d & 255) << 16);
    }
}

__global__ __launch_bounds__(256) void partC_k(const int* __restrict__ packed, const int* __restrict__ starts,
                                               int* __restrict__ off, int* __restrict__ esrc,
                                               int N, int E, int nbuk) {
    __shared__ int lcnt[256];
    __shared__ int lpre[256];
    const int b = blockIdx.x;
    const int bstart = starts[b * NBLKB];
    const int bend = (b + 1 < nbuk) ? starts[(b + 1) * NBLKB] : E;
    const int tid = threadIdx.x;
    lcnt[tid] = 0;
    __syncthreads();
    for (int i = bstart + tid; i < bend; i += 256) atomicAdd(&lcnt[packed[i] >> 16], 1);
    __syncthreads();
    if (tid < 64) {
        int v0 = lcnt[tid * 4], v1 = lcnt[tid * 4 + 1], v2 = lcnt[tid * 4 + 2], v3 = lcnt[tid * 4 + 3];
        int s = v0 + v1 + v2 + v3;
        int inc = s;
        #pragma unroll
        for (int d = 1; d < 64; d <<= 1) {
            int t = __shfl_up(inc, d);
            if (tid >= d) inc += t;
        }
        int ex = inc - s;
        lpre[tid * 4] = ex;
        lpre[tid * 4 + 1] = ex + v0;
        lpre[tid * 4 + 2] = ex + v0 + v1;
        lpre[tid * 4 + 3] = ex + v0 + v1 + v2;
    }
    __syncthreads();
    const int n0 = b << 8;
    const int nn = min(256, N - n0);
    if (tid < nn) off[n0 + tid] = bstart + lpre[tid];
    if (b == 0 && tid == 0) off[N] = E;
    lcnt[tid] = 0;
    __syncthreads();
    for (int i = bstart + tid; i < bend; i += 256) {
        int p = packed[i];
        int ld = p >> 16;
        int slot = atomicAdd(&lcnt[ld], 1);
        esrc[bstart + lpre[ld] + slot] = p & 0xFFFF;
    }
}

// ---------------- GEMM body (templated input type) ----------------

template <int M, int H, typename XT>
__device__ __forceinline__ void gemm_body(float* xsT, float* wt,
                                          const XT* __restrict__ X, const float* __restrict__ W,
                                          const float* __restrict__ a_s, const float* __restrict__ a_d,
                                          __half* __restrict__ O, float* __restrict__ aS,
                                          float* __restrict__ aD, int N, int bid) {
    constexpr int K = 128, BK = 16, ROWS = 128;
    constexpr int CPT = 8;
    constexpr int CT = M / CPT;
    constexpr int RPT = ROWS / (256 / CT);
    constexpr int XP = ROWS + 4;
    constexpr int C = M / H;
    constexpr int REDW = C / CPT;

    const int tid = threadIdx.x;
    const int cc = tid % CT;
    const int rr = tid / CT;
    const int row0 = bid * ROWS;

    float acc[RPT][CPT];
    #pragma unroll
    for (int r = 0; r < RPT; ++r)
        #pragma unroll
        for (int j = 0; j < CPT; ++j) acc[r][j] = 0.f;

    for (int k0 = 0; k0 < K; k0 += BK) {
        #pragma unroll
        for (int t = tid; t < ROWS * (BK / 4); t += 256) {
            int r = t >> 2;
            int kk = t & 3;
            int row = row0 + r;
            float4 v = make_float4(0.f, 0.f, 0.f, 0.f);
            if (row < N) {
                if constexpr (sizeof(XT) == 2) {
                    uint2 raw = *reinterpret_cast<const uint2*>(&X[(size_t)row * K + k0 + kk * 4]);
                    float2 fa = __half22float2(*reinterpret_cast<__half2*>(&raw.x));
                    float2 fb = __half22float2(*reinterpret_cast<__half2*>(&raw.y));
                    v = make_float4(fa.x, fa.y, fb.x, fb.y);
                } else {
                    v = *reinterpret_cast<const float4*>(&X[(size_t)row * K + k0 + kk * 4]);
                }
            }
            xsT[(kk * 4 + 0) * XP + r] = v.x;
            xsT[(kk * 4 + 1) * XP + r] = v.y;
            xsT[(kk * 4 + 2) * XP + r] = v.z;
            xsT[(kk * 4 + 3) * XP + r] = v.w;
        }
        #pragma unroll
        for (int t = tid; t < BK * (M / 4); t += 256) {
            int c4 = t % (M / 4);
            int k = t / (M / 4);
            *reinterpret_cast<float4*>(&wt[k * M + c4 * 4]) =
                *reinterpret_cast<const float4*>(&W[(size_t)(k0 + k) * M + c4 * 4]);
        }
        __syncthreads();
        #pragma unroll
        for (int k = 0; k < BK; ++k) {
            float xr[RPT];
            #pragma unroll
            for (int r4 = 0; r4 < RPT; r4 += 4) {
                float4 xv = *reinterpret_cast<const float4*>(&xsT[k * XP + rr * RPT + r4]);
                xr[r4 + 0] = xv.x; xr[r4 + 1] = xv.y; xr[r4 + 2] = xv.z; xr[r4 + 3] = xv.w;
            }
            float wv[CPT];
            #pragma unroll
            for (int c4 = 0; c4 < CPT; c4 += 4) {
                float4 w4 = *reinterpret_cast<const float4*>(&wt[k * M + cc * CPT + c4]);
                wv[c4 + 0] = w4.x; wv[c4 + 1] = w4.y; wv[c4 + 2] = w4.z; wv[c4 + 3] = w4.w;
            }
            #pragma unroll
            for (int r = 0; r < RPT; ++r)
                #pragma unroll
                for (int j = 0; j < CPT; ++j)
                    acc[r][j] = fmaf(xr[r], wv[j], acc[r][j]);
        }
        __syncthreads();
    }

    float asr[CPT], adr[CPT];
    #pragma unroll
    for (int c4 = 0; c4 < CPT; c4 += 4) {
        float4 t1 = *reinterpret_cast<const float4*>(a_s + cc * CPT + c4);
        asr[c4 + 0] = t1.x; asr[c4 + 1] = t1.y; asr[c4 + 2] = t1.z; asr[c4 + 3] = t1.w;
        float4 t2 = *reinterpret_cast<const float4*>(a_d + cc * CPT + c4);
        adr[c4 + 0] = t2.x; adr[c4 + 1] = t2.y; adr[c4 + 2] = t2.z; adr[c4 + 3] = t2.w;
    }
    const int head = (cc * CPT) / C;

    #pragma unroll
    for (int r = 0; r < RPT; ++r) {
        int row = row0 + rr * RPT + r;
        float ps = 0.f, pd = 0.f;
        #pragma unroll
        for (int j = 0; j < CPT; ++j) {
            ps = fmaf(acc[r][j], asr[j], ps);
            pd = fmaf(acc[r][j], adr[j], pd);
        }
        #pragma unroll
        for (int d = 1; d < REDW; d <<= 1) {
            ps += __shfl_xor(ps, d);
            pd += __shfl_xor(pd, d);
        }
        if (row < N) {
            __half2 p0 = __float22half2_rn(make_float2(acc[r][0], acc[r][1]));
            __half2 p1 = __float22half2_rn(make_float2(acc[r][2], acc[r][3]));
            __half2 p2 = __float22half2_rn(make_float2(acc[r][4], acc[r][5]));
            __half2 p3 = __float22half2_rn(make_float2(acc[r][6], acc[r][7]));
            uint4 pk;
            pk.x = *reinterpret_cast<unsigned*>(&p0);
            pk.y = *reinterpret_cast<unsigned*>(&p1);
            pk.z = *reinterpret_cast<unsigned*>(&p2);
            pk.w = *reinterpret_cast<unsigned*>(&p3);
            *reinterpret_cast<uint4*>(&O[(size_t)row * M + cc * CPT]) = pk;
            if ((cc & (REDW - 1)) == 0) {
                aS[(size_t)row * H + head] = ps;
                aD[(size_t)row * H + head] = pd;
            }
        }
    }
}

template <int M, int H, typename XT>
__global__ __launch_bounds__(256, 2) void gemm_k(const XT* __restrict__ X, const float* __restrict__ W,
                                                 const float* __restrict__ a_s, const float* __restrict__ a_d,
                                                 __half* __restrict__ O, float* __restrict__ aS,
                                                 float* __restrict__ aD, int N) {
    __shared__ float smem[16 * 132 + 16 * M];
    gemm_body<M, H, XT>(smem, smem + 16 * 132, X, W, a_s, a_d, O, aS, aD, N, blockIdx.x);
}

template <int M, int H>
__global__ __launch_bounds__(256, 2) void gemm_hist_k(const float* __restrict__ X, const float* __restrict__ W,
                                                      const float* __restrict__ a_s, const float* __restrict__ a_d,
                                                      __half* __restrict__ O, float* __restrict__ aS,
                                                      float* __restrict__ aD, int N,
                                                      const int* __restrict__ dst, int E,
                                                      int* __restrict__ cnts, int gemmGrid, int nbuk) {
    __shared__ float smem[16 * 132 + 16 * M];
    if ((int)blockIdx.x < gemmGrid) {
        gemm_body<M, H, float>(smem, smem + 16 * 132, X, W, a_s, a_d, O, aS, aD, N, blockIdx.x);
    } else {
        int* lcnt = (int*)smem;
        const int blk = blockIdx.x - gemmGrid;
        for (int i = threadIdx.x; i < nbuk; i += 256) lcnt[i] = 0;
        __syncthreads();
        const int chunk = (E + NBLKB - 1) / NBLKB;
        const int base = blk * chunk, end = min(base + chunk, E);
        for (int i = base + (int)threadIdx.x; i < end; i += 256) atomicAdd(&lcnt[dst[i] >> 8], 1);
        __syncthreads();
        for (int b = threadIdx.x; b < nbuk; b += 256) cnts[b * NBLKB + blk] = lcnt[b];
    }
}

// ---------------- segment-softmax aggregation: 256 thr, 2 nodes/wave, fp16 payload ----------------
// Fast path: all h-row ids via __shfl; 24 rows (3 batches) issued up-front before
// the weight phase (covers cnt<=24 ~ 98% of nodes); 4th batch refilled if needed.

template <int H, int C, typename OutT>
__global__ __launch_bounds__(256) void agg_k(const __half* __restrict__ h, const float* __restrict__ aS,
                                             const float* __restrict__ aD, const int* __restrict__ off,
                                             const int* __restrict__ esrc, const float* __restrict__ bias,
                                             OutT* __restrict__ out, int N) {
    constexpr int M = H * C;
    constexpr int CPL = M / 32;
    __shared__ float wlds[4][2][32][H];
    const int wslot = threadIdx.x >> 6;
    const int lane  = threadIdx.x & 63;
    const int g     = lane >> 5;
    const int lg    = lane & 31;
    const int node  = (blockIdx.x * 4 + wslot) * 2 + g;
    const bool valid = node < N;
    const int nd = valid ? node : N - 1;

    float adv[H], asv[H];
    if constexpr (H == 4) {
        float4 t = *reinterpret_cast<const float4*>(aD + (size_t)nd * 4);
        adv[0] = t.x; adv[1] = t.y; adv[2] = t.z; adv[3] = t.w;
        float4 u = *reinterpret_cast<const float4*>(aS + (size_t)nd * 4);
        asv[0] = u.x; asv[1] = u.y; asv[2] = u.z; asv[3] = u.w;
    } else {
        adv[0] = aD[nd]; asv[0] = aS[nd];
    }
    float eself[H];
    #pragma unroll
    for (int q = 0; q < H; ++q) eself[q] = leaky(asv[q] + adv[q]);

    const int s0 = off[nd], s1 = off[nd + 1];
    const int deg = s1 - s0;

    if (__all(deg < 32)) {
        const int sv = (lg < deg) ? esrc[s0 + lg] : nd;
        const int ch0 = lg * CPL;
        const int hd = ch0 / C;
        const int cnt = deg + 1;
        const int cmax = max(cnt, __shfl_xor(cnt, 32));
        float wsum = 0.f;

        if constexpr (CPL == 4) {
            uint2 A[8], B[8], Cb[8];
            #pragma unroll
            for (int t = 0; t < 8; ++t) {
                int s = __shfl(sv, t, 32);
                A[t] = *reinterpret_cast<const uint2*>(h + (size_t)s * M + ch0);
            }
            if (cmax > 8) {
                #pragma unroll
                for (int t = 0; t < 8; ++t) {
                    int s = __shfl(sv, 8 + t, 32);
                    B[t] = *reinterpret_cast<const uint2*>(h + (size_t)s * M + ch0);
                }
            }
            if (cmax > 16) {
                #pragma unroll
                for (int t = 0; t < 8; ++t) {
                    int s = __shfl(sv, 16 + t, 32);
                    Cb[t] = *reinterpret_cast<const uint2*>(h + (size_t)s * M + ch0);
                }
            }
            // weight phase (overlaps the h loads)
            {
                float4 u = *reinterpret_cast<const float4*>(aS + (size_t)sv * 4);
                float4 wv;
                if (lg < deg) {
                    wv.x = __expf(leaky(u.x + adv[0]));
                    wv.y = __expf(leaky(u.y + adv[1]));
                    wv.z = __expf(leaky(u.z + adv[2]));
                    wv.w = __expf(leaky(u.w + adv[3]));
                } else if (lg == deg) {
                    wv = make_float4(__expf(eself[0]), __expf(eself[1]), __expf(eself[2]), __expf(eself[3]));
                } else {
                    wv = make_float4(0.f, 0.f, 0.f, 0.f);
                }
                *reinterpret_cast<float4*>(&wlds[wslot][g][lg][0]) = wv;
            }
            asm volatile("s_waitcnt lgkmcnt(0)" ::: "memory");

            float acc0 = 0.f, acc1 = 0.f, acc2 = 0.f, acc3 = 0.f;
            auto consume = [&](uint2 (&buf)[8], int j) {
                #pragma unroll
                for (int t = 0; t < 8; ++t) {
                    float wq = wlds[wslot][g][j + t][hd];
                    wsum += wq;
                    float2 fa = __half22float2(*reinterpret_cast<__half2*>(&buf[t].x));
                    float2 fb = __half22float2(*reinterpret_cast<__half2*>(&buf[t].y));
                    acc0 = fmaf(wq, fa.x, acc0);
                    acc1 = fmaf(wq, fa.y, acc1);
                    acc2 = fmaf(wq, fb.x, acc2);
                    acc3 = fmaf(wq, fb.y, acc3);
                }
            };
            consume(A, 0);
            if (cmax > 8) {
                if (cmax > 24) {
                    #pragma unroll
                    for (int t = 0; t < 8; ++t) {
                        int s = __shfl(sv, 24 + t, 32);
                        A[t] = *reinterpret_cast<const uint2*>(h + (size_t)s * M + ch0);
                    }
                }
                consume(B, 8);
                if (cmax > 16) {
                    consume(Cb, 16);
                    if (cmax > 24) consume(A, 24);
                }
            }
            if (valid) {
                float inv = 1.f / (wsum + EPS_F);
                float4 bb = *reinterpret_cast<const float4*>(bias + ch0);
                float o0 = acc0 * inv + bb.x, o1 = acc1 * inv + bb.y;
                float o2 = acc2 * inv + bb.z, o3 = acc3 * inv + bb.w;
                if constexpr (sizeof(OutT) == 4) {
                    *reinterpret_cast<float4*>((float*)out + (size_t)nd * M + ch0) = make_float4(o0, o1, o2, o3);
                } else {
                    __half2 q0 = __float22half2_rn(make_float2(o0, o1));
                    __half2 q1 = __float22half2_rn(make_float2(o2, o3));
                    uint2 pk;
                    pk.x = *reinterpret_cast<unsigned*>(&q0);
                    pk.y = *reinterpret_cast<unsigned*>(&q1);
                    *reinterpret_cast<uint2*>((__half*)out + (size_t)nd * M + ch0) = pk;
                }
            }
        } else {
            unsigned A[8], B[8], Cb[8];
            #pragma unroll
            for (int t = 0; t < 8; ++t) {
                int s = __shfl(sv, t, 32);
                A[t] = *reinterpret_cast<const unsigned*>(h + (size_t)s * M + ch0);
            }
            if (cmax > 8) {
                #pragma unroll
                for (int t = 0; t < 8; ++t) {
                    int s = __shfl(sv, 8 + t, 32);
                    B[t] = *reinterpret_cast<const unsigned*>(h + (size_t)s * M + ch0);
                }
            }
            if (cmax > 16) {
                #pragma unroll
                for (int t = 0; t < 8; ++t) {
                    int s = __shfl(sv, 16 + t, 32);
                    Cb[t] = *reinterpret_cast<const unsigned*>(h + (size_t)s * M + ch0);
                }
            }
            {
                float u = aS[sv];
                wlds[wslot][g][lg][0] = (lg < deg) ? __expf(leaky(u + adv[0]))
                                      : (lg == deg) ? __expf(eself[0]) : 0.f;
            }
            asm volatile("s_waitcnt lgkmcnt(0)" ::: "memory");

            float acc0 = 0.f, acc1 = 0.f;
            auto consume = [&](unsigned (&buf)[8], int j) {
                #pragma unroll
                for (int t = 0; t < 8; ++t) {
                    float wq = wlds[wslot][g][j + t][0];
                    wsum += wq;
                    float2 fa = __half22float2(*reinterpret_cast<__half2*>(&buf[t]));
                    acc0 = fmaf(wq, fa.x, acc0);
                    acc1 = fmaf(wq, fa.y, acc1);
                }
            };
            consume(A, 0);
            if (cmax > 8) {
                if (cmax > 24) {
                    #pragma unroll
                    for (int t = 0; t < 8; ++t) {
                        int s = __shfl(sv, 24 + t, 32);
                        A[t] = *reinterpret_cast<const unsigned*>(h + (size_t)s * M + ch0);
                    }
                }
                consume(B, 8);
                if (cmax > 16) {
                    consume(Cb, 16);
                    if (cmax > 24) consume(A, 24);
                }
            }
            if (valid) {
                float inv = 1.f / (wsum + EPS_F);
                float o0 = acc0 * inv + bias[ch0];
                float o1 = acc1 * inv + bias[ch0 + 1];
                if constexpr (sizeof(OutT) == 4) {
                    *reinterpret_cast<float2*>((float*)out + (size_t)nd * M + ch0) = make_float2(o0, o1);
                } else {
                    __half2 q0 = __float22half2_rn(make_float2(o0, o1));
                    *reinterpret_cast<unsigned*>((__half*)out + (size_t)nd * M + ch0) =
                        *reinterpret_cast<unsigned*>(&q0);
                }
            }
        }
    } else {
        constexpr int CPL64 = M / 64;
        const int ch = lane * CPL64;
        const int hh = ch / C;
        #pragma unroll 1
        for (int i = 0; i < 2; ++i) {
            int fn = (blockIdx.x * 4 + wslot) * 2 + i;
            if (fn >= N) continue;
            float fadv[H], fes[H];
            if constexpr (H == 4) {
                float4 t = *reinterpret_cast<const float4*>(aD + (size_t)fn * 4);
                fadv[0] = t.x; fadv[1] = t.y; fadv[2] = t.z; fadv[3] = t.w;
                float4 u = *reinterpret_cast<const float4*>(aS + (size_t)fn * 4);
                fes[0] = leaky(u.x + t.x); fes[1] = leaky(u.y + t.y);
                fes[2] = leaky(u.z + t.z); fes[3] = leaky(u.w + t.w);
            } else {
                fadv[0] = aD[fn];
                fes[0] = leaky(aS[fn] + fadv[0]);
            }
            int fs0 = off[fn], fs1 = off[fn + 1];
            float m[H], ds[H];
            #pragma unroll
            for (int q = 0; q < H; ++q) { m[q] = fes[q]; ds[q] = 0.f; }
            for (int e = fs0 + lane; e < fs1; e += 64) {
                int s = esrc[e];
                if constexpr (H == 4) {
                    float4 u = *reinterpret_cast<const float4*>(aS + (size_t)s * 4);
                    float evv[4] = {u.x, u.y, u.z, u.w};
                    #pragma unroll
                    for (int q = 0; q < 4; ++q) {
                        float ee = leaky(evv[q] + fadv[q]);
                        float nm = fmaxf(m[q], ee);
                        ds[q] = ds[q] * __expf(m[q] - nm) + __expf(ee - nm);
                        m[q] = nm;
                    }
                } else {
                    float ee = leaky(aS[s] + fadv[0]);
                    float nm = fmaxf(m[0], ee);
                    ds[0] = ds[0] * __expf(m[0] - nm) + __expf(ee - nm);
                    m[0] = nm;
                }
            }
            #pragma unroll
            for (int q = 0; q < H; ++q) {
                #pragma unroll
                for (int d = 1; d < 64; d <<= 1) {
                    float om = __shfl_xor(m[q], d);
                    float od = __shfl_xor(ds[q], d);
                    float nm = fmaxf(m[q], om);
                    ds[q] = ds[q] * __expf(m[q] - nm) + od * __expf(om - nm);
                    m[q] = nm;
                }
                ds[q] += __expf(fes[q] - m[q]);
            }
            float a0 = 0.f, a1 = 0.f;
            for (int e = fs0; e < fs1; ++e) {
                int s = esrc[e];
                float wq = __expf(leaky(aS[(size_t)s * H + hh] + fadv[hh]) - m[hh]);
                if constexpr (CPL64 == 2) {
                    float2 f = __half22float2(*reinterpret_cast<const __half2*>(h + (size_t)s * M + ch));
                    a0 = fmaf(wq, f.x, a0);
                    a1 = fmaf(wq, f.y, a1);
                } else {
                    a0 = fmaf(wq, __half2float(h[(size_t)s * M + ch]), a0);
                }
            }
            {
                float wq = __expf(fes[hh] - m[hh]);
                if constexpr (CPL64 == 2) {
                    float2 f = __half22float2(*reinterpret_cast<const __half2*>(h + (size_t)fn * M + ch));
                    a0 = fmaf(wq, f.x, a0);
                    a1 = fmaf(wq, f.y, a1);
                } else {
                    a0 = fmaf(wq, __half2float(h[(size_t)fn * M + ch]), a0);
                }
            }
            float inv = 1.f / (ds[hh] + EPS_F);
            if constexpr (CPL64 == 2) {
                float o0 = a0 * inv + bias[ch], o1 = a1 * inv + bias[ch + 1];
                if constexpr (sizeof(OutT) == 4) {
                    *reinterpret_cast<float2*>((float*)out + (size_t)fn * M + ch) = make_float2(o0, o1);
                } else {
                    __half2 q0 = __float22half2_rn(make_float2(o0, o1));
                    *reinterpret_cast<unsigned*>((__half*)out + (size_t)fn * M + ch) =
                        *reinterpret_cast<unsigned*>(&q0);
                }
            } else {
                float o0 = a0 * inv + bias[ch];
                if constexpr (sizeof(OutT) == 4) ((float*)out)[(size_t)fn * M + ch] = o0;
                else ((__half*)out)[(size_t)fn * M + ch] = __float2half_rn(o0);
            }
        }
    }
}

// ---------------- launch ----------------

extern "C" void kernel_launch(void* const* d_in, const int* in_sizes, int n_in,
                              void* d_out, int out_size, void* d_ws, size_t ws_size,
                              hipStream_t stream) {
    const float* x   = (const float*)d_in[0];
    const int*   ei  = (const int*)d_in[1];
    const float* W0  = (const float*)d_in[2];
    const float* as0 = (const float*)d_in[3];
    const float* ad0 = (const float*)d_in[4];
    const float* b0  = (const float*)d_in[5];
    const float* W1  = (const float*)d_in[6];
    const float* as1 = (const float*)d_in[7];
    const float* ad1 = (const float*)d_in[8];
    const float* b1  = (const float*)d_in[9];
    const float* W2  = (const float*)d_in[10];
    const float* as2 = (const float*)d_in[11];
    const float* ad2 = (const float*)d_in[12];
    const float* b2  = (const float*)d_in[13];

    const int N = in_sizes[0] / 128;  // 50000
    const int E = in_sizes[1] / 2;    // 800000
    const int* esrc_in = ei;
    const int* edst_in = ei + E;
    const int NBUK = (N + 255) >> 8;  // 196

    char* w = (char*)d_ws;
    auto carve = [&](size_t bytes) -> char* {
        char* p = w;
        w += (bytes + 255) & ~(size_t)255;
        return p;
    };
    int*    off    = (int*)carve((size_t)(N + 1) * 4);
    int*    es     = (int*)carve((size_t)E * 4);
    int*    cnts   = (int*)carve((size_t)NBUK * NBLKB * 4);
    int*    starts = (int*)carve(((size_t)NBUK * NBLKB + 1) * 4);
    int*    packed = (int*)carve((size_t)E * 4);
    float*  aS     = (float*)carve((size_t)N * 4 * sizeof(float));
    float*  aD     = (float*)carve((size_t)N * 4 * sizeof(float));
    __half* bufH   = (__half*)carve((size_t)N * 128 * sizeof(__half));
    __half* bufO   = (__half*)carve((size_t)N * 128 * sizeof(__half));
    (void)ws_size; (void)n_in; (void)out_size;

    const int GEMM_GRID = (N + 127) / 128;
    const int AGG_GRID = (N + 7) / 8;

    gemm_hist_k<128, 4><<<GEMM_GRID + NBLKB, 256, 0, stream>>>(x, W0, as0, ad0, bufH, aS, aD, N,
                                                               edst_in, E, cnts, GEMM_GRID, NBUK);
    scan_k<<<1, 1024, 0, stream>>>(cnts, starts, NBUK * NBLKB);
    partB_k<<<NBLKB, 256, 0, stream>>>(esrc_in, edst_in, starts, packed, E, NBUK);
    partC_k<<<NBUK, 256, 0, stream>>>(packed, starts, off, es, N, E, NBUK);

    agg_k<4, 32, __half><<<AGG_GRID, 256, 0, stream>>>(bufH, aS, aD, off, es, b0, bufO, N);

    gemm_k<128, 4, __half><<<GEMM_GRID, 256, 0, stream>>>(bufO, W1, as1, ad1, bufH, aS, aD, N);
    agg_k<4, 32, __half><<<AGG_GRID, 256, 0, stream>>>(bufH, aS, aD, off, es, b1, bufO, N);

    gemm_k<64, 1, __half><<<GEMM_GRID, 256, 0, stream>>>(bufO, W2, as2, ad2, bufH, aS, aD, N);
    agg_k<1, 64, float><<<AGG_GRID, 256, 0, stream>>>(bufH, aS, aD, off, es, b2, (float*)d_out, N);
}